// Round 5
// baseline (623.416 us; speedup 1.0000x reference)
//
#include <hip/hip_runtime.h>
#include <hip/hip_bf16.h>

#define B_   2
#define T_   2048
#define D_   1024
#define NH_  16
#define HD_  64
#define HID_ 4096
#define CD_  1024
#define SIX_D (6*D_)

typedef __bf16 bf16x8 __attribute__((ext_vector_type(8)));
typedef float  f32x4  __attribute__((ext_vector_type(4)));

__device__ __forceinline__ unsigned short f2bf(float f){
  union { float f; unsigned u; } v; v.f = f;
  unsigned r = v.u + 0x7FFFu + ((v.u >> 16) & 1u);
  return (unsigned short)(r >> 16);
}
__device__ __forceinline__ float bf2f(unsigned short u){
  union { unsigned x; float f; } v; v.x = ((unsigned)u) << 16; return v.f;
}

__device__ __forceinline__ void gl_lds16(const void* g, void* l){
  __builtin_amdgcn_global_load_lds(
      (__attribute__((address_space(1))) void*)const_cast<void*>(g),
      (__attribute__((address_space(3))) void*)l, 16, 0, 0);
}

// ---------------- all weights fp32 -> bf16, single launch ----------------
// Each block converts 256 float4 = 1024 elements.
// Block counts: qkv 3072 | proj 1024 | fc1 8192 | fc2 4096 => 16384 total
__global__ void k_conv_all(const float* __restrict__ s0, const float* __restrict__ s1,
                           const float* __restrict__ s2, const float* __restrict__ s3,
                           unsigned short* __restrict__ d0, unsigned short* __restrict__ d1,
                           unsigned short* __restrict__ d2, unsigned short* __restrict__ d3){
  int bid = blockIdx.x;
  const float* s; unsigned short* d; int base;
  if (bid < 3072)      { s = s0; d = d0; base = bid; }
  else if (bid < 4096) { s = s1; d = d1; base = bid - 3072; }
  else if (bid < 12288){ s = s2; d = d2; base = bid - 4096; }
  else                 { s = s3; d = d3; base = bid - 12288; }
  int i = base*256 + threadIdx.x;
  float4 v = reinterpret_cast<const float4*>(s)[i];
  ushort4 o;
  o.x = f2bf(v.x); o.y = f2bf(v.y); o.z = f2bf(v.z); o.w = f2bf(v.w);
  reinterpret_cast<ushort4*>(d)[i] = o;
}

// ---------------- ada = silu(cond) @ ada_w.T + ada_b ----------------
__global__ void k_ada(const float* __restrict__ cond, const float* __restrict__ ada_w,
                      const float* __restrict__ ada_b, float* __restrict__ ada){
  __shared__ float sc[CD_];
  int b = blockIdx.y;
  int tid = threadIdx.x;
  for (int i = tid; i < CD_; i += 256){
    float c = cond[b*CD_ + i];
    sc[i] = c / (1.f + __expf(-c));
  }
  __syncthreads();
  int col = blockIdx.x*256 + tid;
  const float* wr = ada_w + (size_t)col*CD_;
  float acc = 0.f;
  #pragma unroll 4
  for (int k = 0; k < CD_; k++) acc += sc[k]*wr[k];
  ada[b*SIX_D + col] = acc + ada_b[col];
}

// ---------------- rmsnorm + modulate -> bf16 ----------------
__global__ void k_norm_mod(const float* __restrict__ x, const float* __restrict__ w,
                           const float* __restrict__ ada, int sh_off, int sc_off,
                           unsigned short* __restrict__ out){
  int row = blockIdx.x;           // b*T + t
  int b = row >> 11;              // / T_
  int tid = threadIdx.x;
  float4 xv = reinterpret_cast<const float4*>(x + (size_t)row*D_)[tid];
  float ss = xv.x*xv.x + xv.y*xv.y + xv.z*xv.z + xv.w*xv.w;
  #pragma unroll
  for (int m = 32; m > 0; m >>= 1) ss += __shfl_xor(ss, m, 64);
  __shared__ float red[4];
  int wave = tid >> 6;
  if ((tid & 63) == 0) red[wave] = ss;
  __syncthreads();
  float tot = red[0]+red[1]+red[2]+red[3];
  float rn = rsqrtf(tot * (1.f/(float)D_) + 1e-6f);
  float4 wv  = reinterpret_cast<const float4*>(w)[tid];
  float4 scv = reinterpret_cast<const float4*>(ada + b*SIX_D + sc_off)[tid];
  float4 shv = reinterpret_cast<const float4*>(ada + b*SIX_D + sh_off)[tid];
  ushort4 o;
  o.x = f2bf(xv.x*rn*wv.x*(1.f+scv.x)+shv.x);
  o.y = f2bf(xv.y*rn*wv.y*(1.f+scv.y)+shv.y);
  o.z = f2bf(xv.z*rn*wv.z*(1.f+scv.z)+shv.z);
  o.w = f2bf(xv.w*rn*wv.w*(1.f+scv.w)+shv.w);
  reinterpret_cast<ushort4*>(out + (size_t)row*D_)[tid] = o;
}

// ---------------- 128x128 GEMM: C = A(MxK) * W(NxK)^T ----------------
enum { EPI_F32 = 0, EPI_RESID = 1, EPI_BF16 = 2 };

template<int EPI>
__launch_bounds__(256)
__global__ void k_gemm_bt(const unsigned short* __restrict__ A,
                          const unsigned short* __restrict__ W,
                          int M, int N, int K,
                          void* __restrict__ outp,
                          const float* __restrict__ resid,
                          const float* __restrict__ ada, int g_off,
                          const float* __restrict__ bias){
  __shared__ __align__(16) unsigned short As[128*32];
  __shared__ __align__(16) unsigned short Bs[128*32];
  const int tid = threadIdx.x;
  const int wave = tid >> 6, lane = tid & 63;
  const int wm = (wave >> 1)*64, wn = (wave & 1)*64;
  const int m0 = blockIdx.y*128, n0 = blockIdx.x*128;
  const int fr = lane & 15, fq = lane >> 4;
  f32x4 acc[4][4] = {};
  for (int k0 = 0; k0 < K; k0 += 32){
    __syncthreads();
    #pragma unroll
    for (int rr = 0; rr < 2; rr++){
      int idx = rr*256 + tid;
      int row = idx >> 2, c8 = (idx & 3)*8;
      gl_lds16(A + (size_t)(m0 + row)*K + k0 + c8, &As[(idx & ~63)*8]);
      gl_lds16(W + (size_t)(n0 + row)*K + k0 + c8, &Bs[(idx & ~63)*8]);
    }
    __syncthreads();
    bf16x8 af[4], bfr[4];
    #pragma unroll
    for (int i = 0; i < 4; i++){
      af[i]  = *(const bf16x8*)&As[(wm + i*16 + fr)*32 + fq*8];
      bfr[i] = *(const bf16x8*)&Bs[(wn + i*16 + fr)*32 + fq*8];
    }
    #pragma unroll
    for (int i = 0; i < 4; i++)
      #pragma unroll
      for (int j = 0; j < 4; j++)
        acc[i][j] = __builtin_amdgcn_mfma_f32_16x16x32_bf16(af[i], bfr[j], acc[i][j], 0,0,0);
  }
  #pragma unroll
  for (int i = 0; i < 4; i++){
    #pragma unroll
    for (int j = 0; j < 4; j++){
      int col = n0 + wn + j*16 + fr;
      #pragma unroll
      for (int r = 0; r < 4; r++){
        int row = m0 + wm + i*16 + fq*4 + r;
        float v = acc[i][j][r];
        if (EPI == EPI_F32){
          ((float*)outp)[(size_t)row*N + col] = v;
        } else if (EPI == EPI_BF16){
          ((unsigned short*)outp)[(size_t)row*N + col] = f2bf(v);
        } else {
          int b = row >> 11;
          float g = ada[b*SIX_D + g_off + col];
          ((float*)outp)[(size_t)row*N + col] = resid[(size_t)row*N + col] + g*(v + bias[col]);
        }
      }
    }
  }
}

// ---------------- 64x128 GEMM (for N=1024 shapes: proj, fc2) ----------------
template<int EPI>
__launch_bounds__(256)
__global__ void k_gemm_bt64(const unsigned short* __restrict__ A,
                            const unsigned short* __restrict__ W,
                            int M, int N, int K,
                            void* __restrict__ outp,
                            const float* __restrict__ resid,
                            const float* __restrict__ ada, int g_off,
                            const float* __restrict__ bias){
  __shared__ __align__(16) unsigned short As[64*32];
  __shared__ __align__(16) unsigned short Bs[128*32];
  const int tid = threadIdx.x;
  const int wave = tid >> 6, lane = tid & 63;
  const int wm = (wave >> 1)*32, wn = (wave & 1)*64;
  const int m0 = blockIdx.y*64, n0 = blockIdx.x*128;
  const int fr = lane & 15, fq = lane >> 4;
  f32x4 acc[2][4] = {};
  for (int k0 = 0; k0 < K; k0 += 32){
    __syncthreads();
    {
      int row = tid >> 2, c8 = (tid & 3)*8;
      gl_lds16(A + (size_t)(m0 + row)*K + k0 + c8, &As[(tid & ~63)*8]);
    }
    #pragma unroll
    for (int rr = 0; rr < 2; rr++){
      int idx = rr*256 + tid;
      int row = idx >> 2, c8 = (idx & 3)*8;
      gl_lds16(W + (size_t)(n0 + row)*K + k0 + c8, &Bs[(idx & ~63)*8]);
    }
    __syncthreads();
    bf16x8 af[2], bfr[4];
    #pragma unroll
    for (int i = 0; i < 2; i++)
      af[i]  = *(const bf16x8*)&As[(wm + i*16 + fr)*32 + fq*8];
    #pragma unroll
    for (int j = 0; j < 4; j++)
      bfr[j] = *(const bf16x8*)&Bs[(wn + j*16 + fr)*32 + fq*8];
    #pragma unroll
    for (int i = 0; i < 2; i++)
      #pragma unroll
      for (int j = 0; j < 4; j++)
        acc[i][j] = __builtin_amdgcn_mfma_f32_16x16x32_bf16(af[i], bfr[j], acc[i][j], 0,0,0);
  }
  #pragma unroll
  for (int i = 0; i < 2; i++){
    #pragma unroll
    for (int j = 0; j < 4; j++){
      int col = n0 + wn + j*16 + fr;
      #pragma unroll
      for (int r = 0; r < 4; r++){
        int row = m0 + wm + i*16 + fq*4 + r;
        float v = acc[i][j][r];
        if (EPI == EPI_F32){
          ((float*)outp)[(size_t)row*N + col] = v;
        } else if (EPI == EPI_BF16){
          ((unsigned short*)outp)[(size_t)row*N + col] = f2bf(v);
        } else {
          int b = row >> 11;
          float g = ada[b*SIX_D + g_off + col];
          ((float*)outp)[(size_t)row*N + col] = resid[(size_t)row*N + col] + g*(v + bias[col]);
        }
      }
    }
  }
}

// ---------------- fc1 dual 128x(64+64) with fused SwiGLU -> bf16 ----------------
__launch_bounds__(256)
__global__ void k_gemm_fc1(const unsigned short* __restrict__ A,
                           const unsigned short* __restrict__ W,   // (2*HID, D) bf16
                           const float* __restrict__ bias,          // (2*HID)
                           unsigned short* __restrict__ out){       // (B*T, HID) bf16
  __shared__ __align__(16) unsigned short As[128*32];
  __shared__ __align__(16) unsigned short Bv[64*32];
  __shared__ __align__(16) unsigned short Bg[64*32];
  const int K = D_;
  const int tid = threadIdx.x;
  const int wave = tid >> 6, lane = tid & 63;
  const int wm = (wave >> 1)*64, wn = (wave & 1)*32;
  const int m0 = blockIdx.y*128, n0 = blockIdx.x*64;
  const int fr = lane & 15, fq = lane >> 4;
  f32x4 accv[4][2] = {}, accg[4][2] = {};
  for (int k0 = 0; k0 < K; k0 += 32){
    __syncthreads();
    #pragma unroll
    for (int rr = 0; rr < 2; rr++){
      int idx = rr*256 + tid;
      int row = idx >> 2, c8 = (idx & 3)*8;
      gl_lds16(A + (size_t)(m0 + row)*K + k0 + c8, &As[(idx & ~63)*8]);
    }
    {
      int row = tid >> 2, c8 = (tid & 3)*8;
      gl_lds16(W + (size_t)(n0 + row)*K + k0 + c8,        &Bv[(tid & ~63)*8]);
      gl_lds16(W + (size_t)(HID_ + n0 + row)*K + k0 + c8, &Bg[(tid & ~63)*8]);
    }
    __syncthreads();
    bf16x8 af[4], bv[2], bg[2];
    #pragma unroll
    for (int i = 0; i < 4; i++)
      af[i] = *(const bf16x8*)&As[(wm + i*16 + fr)*32 + fq*8];
    #pragma unroll
    for (int j = 0; j < 2; j++){
      bv[j] = *(const bf16x8*)&Bv[(wn + j*16 + fr)*32 + fq*8];
      bg[j] = *(const bf16x8*)&Bg[(wn + j*16 + fr)*32 + fq*8];
    }
    #pragma unroll
    for (int i = 0; i < 4; i++)
      #pragma unroll
      for (int j = 0; j < 2; j++){
        accv[i][j] = __builtin_amdgcn_mfma_f32_16x16x32_bf16(af[i], bv[j], accv[i][j], 0,0,0);
        accg[i][j] = __builtin_amdgcn_mfma_f32_16x16x32_bf16(af[i], bg[j], accg[i][j], 0,0,0);
      }
  }
  #pragma unroll
  for (int i = 0; i < 4; i++){
    #pragma unroll
    for (int j = 0; j < 2; j++){
      int col = n0 + wn + j*16 + fr;
      #pragma unroll
      for (int r = 0; r < 4; r++){
        int row = m0 + wm + i*16 + fq*4 + r;
        float vv = accv[i][j][r] + bias[col];
        float gg = accg[i][j][r] + bias[HID_ + col];
        float h = vv * (gg / (1.f + __expf(-gg)));
        out[(size_t)row*HID_ + col] = f2bf(h);
      }
    }
  }
}

// ---------------- qkv(bf16) -> q,k with per-head rmsnorm + rope -> bf16 (B,NH,T,HD) ----------------
__global__ void k_qkv_post(const unsigned short* __restrict__ qkv,
                           const float* __restrict__ qw, const float* __restrict__ kw,
                           const int* __restrict__ wptr,
                           unsigned short* __restrict__ q, unsigned short* __restrict__ k){
  int idx = blockIdx.x;           // (b*T + t)*NH + h
  int h = idx & (NH_-1);
  int t = (idx >> 4) & (T_-1);
  int b = idx >> 15;
  int d = threadIdx.x;            // 0..63
  const unsigned short* base = qkv + (size_t)(b*T_ + t)*3072;
  float qv = bf2f(base[h*64 + d]);
  float kv = bf2f(base[1024 + h*64 + d]);
  float sq = qv*qv, sk = kv*kv;
  #pragma unroll
  for (int m = 32; m > 0; m >>= 1){ sq += __shfl_xor(sq, m, 64); sk += __shfl_xor(sk, m, 64); }
  qv *= rsqrtf(sq*(1.f/64.f) + 1e-6f) * qw[d];
  kv *= rsqrtf(sk*(1.f/64.f) + 1e-6f) * kw[d];
  int width = wptr[0];
  int yy = t / width, xx = t - yy*width;
  int coord = (d < 32) ? yy : xx;
  int fi = (d & 31) >> 1;
  float ifreq = __expf(-(float)fi * (9.210340371976184f/16.f));  // 10000^(-fi/16)
  float ang = (float)coord * ifreq;
  float cs = cosf(ang), sn = sinf(ang);
  float pq = __shfl_xor(qv, 1, 64);
  float pk = __shfl_xor(kv, 1, 64);
  float rq = (d & 1) ? pq : -pq;
  float rk = (d & 1) ? pk : -pk;
  qv = qv*cs + rq*sn;
  kv = kv*cs + rk*sn;
  size_t o = ((size_t)(b*NH_ + h)*T_ + t)*64 + d;
  q[o] = f2bf(qv); k[o] = f2bf(kv);
}

// ---------------- V transpose: qkv bf16 (b,t, 2048 + h*64+d) -> vt bf16 (b,h,d,t) ----------------
__global__ void k_vtrans(const unsigned short* __restrict__ qkv, unsigned short* __restrict__ vt){
  __shared__ __align__(16) unsigned short TT[64*64];  // [d][t], groups swizzled
  int bh = blockIdx.y, t0 = blockIdx.x*64;
  int b = bh >> 4, h = bh & 15;
  int tid = threadIdx.x;
  #pragma unroll
  for (int it = 0; it < 2; it++){
    int i2 = it*256 + tid;
    int t = i2 >> 3, c8 = (i2 & 7)*8;
    union { uint4 v; unsigned short u[8]; } ld;
    ld.v = *(const uint4*)(qkv + (size_t)(b*T_ + t0 + t)*3072 + 2048 + h*64 + c8);
    #pragma unroll
    for (int e = 0; e < 8; e++){
      int c = c8 + e;
      int gp = (t >> 3) ^ ((c >> 2) & 7);
      TT[c*64 + gp*8 + (t & 7)] = ld.u[e];
    }
  }
  __syncthreads();
  #pragma unroll
  for (int it = 0; it < 2; it++){
    int i2 = it*256 + tid;
    int d = i2 >> 3, g = i2 & 7;
    int gp = g ^ ((d >> 2) & 7);
    *(uint4*)(vt + ((size_t)(bh*64 + d)*T_ + t0 + g*8)) = *(const uint4*)&TT[d*64 + gp*8];
  }
}

// ---------------- flash attention: full-T stream, XCD-local, coalesced out ----------------
__launch_bounds__(256, 4)
__global__ void k_attn(const unsigned short* __restrict__ q,
                       const unsigned short* __restrict__ k,
                       const unsigned short* __restrict__ vt,
                       unsigned short* __restrict__ out){     // (B,T,D) bf16
  __shared__ __align__(16) unsigned short Ks[64*64];
  __shared__ __align__(16) unsigned short Vs[64*64];
  __shared__ __align__(16) unsigned short Ps[4][32*64];
  const int tid = threadIdx.x;
  const int wave = tid >> 6, lane = tid & 63;
  const int fr = lane & 15, fq = lane >> 4;
  // XCD-locality swizzle: bh in low 5 bits -> all 16 q-tiles of one head share id%8
  const int id = blockIdx.x;
  const int bh = id & 31, q0 = (id >> 5)*128;
  const unsigned short* kb = k  + (size_t)bh*T_*HD_;
  const unsigned short* vb = vt + (size_t)bh*HD_*T_;
  bf16x8 aq[2][2];
  {
    const unsigned short* qb = q + (size_t)bh*T_*HD_;
    #pragma unroll
    for (int i = 0; i < 2; i++)
      #pragma unroll
      for (int kk = 0; kk < 2; kk++)
        aq[i][kk] = *(const bf16x8*)(qb + (size_t)(q0 + wave*32 + i*16 + fr)*HD_ + kk*32 + fq*8);
  }
  f32x4 o[2][4] = {};
  float lsum[2][4] = {};
  for (int kt = 0; kt < T_; kt += 64){
    __syncthreads();
    #pragma unroll
    for (int it = 0; it < 2; it++){
      int i2 = it*256 + tid;
      int row = i2 >> 3, g = i2 & 7, gp = g ^ (row & 7);
      ((uint4*)Ks)[row*8 + gp] = ((const uint4*)kb)[(kt + row)*8 + g];
      ((uint4*)Vs)[row*8 + gp] = ((const uint4*)vb)[row*256 + (kt >> 3) + g];
    }
    __syncthreads();
    // S = Q K^T
    f32x4 s[2][4] = {};
    #pragma unroll
    for (int kk = 0; kk < 2; kk++){
      bf16x8 bk[4];
      #pragma unroll
      for (int j = 0; j < 4; j++)
        bk[j] = *(const bf16x8*)&Ks[(j*16 + fr)*64 + ((kk*4 + fq) ^ (fr & 7))*8];
      #pragma unroll
      for (int i = 0; i < 2; i++)
        #pragma unroll
        for (int j = 0; j < 4; j++)
          s[i][j] = __builtin_amdgcn_mfma_f32_16x16x32_bf16(aq[i][kk], bk[j], s[i][j], 0,0,0);
    }
    // fixed-shift softmax: p = exp(clamp(s/8))
    unsigned short* Pw = Ps[wave];
    #pragma unroll
    for (int i = 0; i < 2; i++)
      #pragma unroll
      for (int j = 0; j < 4; j++)
        #pragma unroll
        for (int r = 0; r < 4; r++){
          float sv = s[i][j][r]*0.125f;
          sv = fminf(fmaxf(sv, -30.f), 30.f);
          float p = __expf(sv);
          lsum[i][r] += p;
          int row = i*16 + fq*4 + r;
          int gp = (j*2 + (fr >> 3)) ^ (row & 7);
          Pw[row*64 + gp*8 + (fr & 7)] = f2bf(p);
        }
    // O += P V
    #pragma unroll
    for (int kk = 0; kk < 2; kk++){
      bf16x8 ap[2], bv[4];
      #pragma unroll
      for (int i = 0; i < 2; i++)
        ap[i] = *(const bf16x8*)&Pw[(i*16 + fr)*64 + ((kk*4 + fq) ^ (fr & 7))*8];
      #pragma unroll
      for (int dn = 0; dn < 4; dn++)
        bv[dn] = *(const bf16x8*)&Vs[(dn*16 + fr)*64 + ((kk*4 + fq) ^ (fr & 7))*8];
      #pragma unroll
      for (int i = 0; i < 2; i++)
        #pragma unroll
        for (int dn = 0; dn < 4; dn++)
          o[i][dn] = __builtin_amdgcn_mfma_f32_16x16x32_bf16(ap[i], bv[dn], o[i][dn], 0,0,0);
    }
  }
  // epilogue: row-sum reduce across fr lanes, normalize, repack via Ps, coalesced store
  #pragma unroll
  for (int i = 0; i < 2; i++)
    #pragma unroll
    for (int r = 0; r < 4; r++){
      float l = lsum[i][r];
      #pragma unroll
      for (int m = 1; m < 16; m <<= 1) l += __shfl_xor(l, m, 64);
      lsum[i][r] = 1.f / l;
    }
  __syncthreads();   // everyone done reading Ps for PV (own-wave, but Vs/Ks reuse safety)
  {
    unsigned short* Pw = Ps[wave];
    #pragma unroll
    for (int i = 0; i < 2; i++)
      #pragma unroll
      for (int dn = 0; dn < 4; dn++)
        #pragma unroll
        for (int r = 0; r < 4; r++){
          int row = i*16 + fq*4 + r;
          int gp = (dn*2 + (fr >> 3)) ^ (row & 7);
          Pw[row*64 + gp*8 + (fr & 7)] = f2bf(o[i][dn][r]*lsum[i][r]);
        }
  }
  __syncthreads();
  const int b = bh >> 4, h = bh & 15;
  const int rowg = tid >> 3, g = tid & 7;
  #pragma unroll
  for (int it = 0; it < 4; it++){
    int row = it*32 + rowg;
    int wsrc = row >> 5, r32 = row & 31;
    int gp = g ^ (r32 & 7);
    uint4 val = *(const uint4*)&Ps[wsrc][r32*64 + gp*8];
    *(uint4*)(out + (size_t)(b*T_ + q0 + row)*D_ + h*64 + g*8) = val;
  }
}

extern "C" void kernel_launch(void* const* d_in, const int* in_sizes, int n_in,
                              void* d_out, int out_size, void* d_ws, size_t ws_size,
                              hipStream_t stream){
  const float* x      = (const float*)d_in[0];
  const float* cond   = (const float*)d_in[1];
  const float* norm1w = (const float*)d_in[2];
  const float* qkv_w  = (const float*)d_in[3];
  const float* q_nw   = (const float*)d_in[4];
  const float* k_nw   = (const float*)d_in[5];
  const float* proj_w = (const float*)d_in[6];
  const float* proj_b = (const float*)d_in[7];
  const float* norm2w = (const float*)d_in[8];
  const float* fc1_w  = (const float*)d_in[9];
  const float* fc1_b  = (const float*)d_in[10];
  const float* fc2_w  = (const float*)d_in[11];
  const float* fc2_b  = (const float*)d_in[12];
  const float* ada_w  = (const float*)d_in[13];
  const float* ada_b  = (const float*)d_in[14];
  const int*   wptr   = (const int*)d_in[16];
  float* out = (float*)d_out;

  char* ws = (char*)d_ws;
  size_t off = 0;
  auto alloc = [&](size_t bytes)->void*{
    void* p = ws + off; off += (bytes + 255) & ~(size_t)255; return p;
  };
  unsigned short* w_qkv  = (unsigned short*)alloc(3072ull*1024*2);
  unsigned short* w_proj = (unsigned short*)alloc(1024ull*1024*2);
  unsigned short* w_fc1  = (unsigned short*)alloc(8192ull*1024*2);
  unsigned short* w_fc2  = (unsigned short*)alloc(1024ull*4096*2);
  float* ada             = (float*)alloc((size_t)B_*SIX_D*4);
  unsigned short* h1     = (unsigned short*)alloc(4096ull*1024*2);
  // region R: qkv_out bf16 (25 MB) lives until k_vtrans; afterwards reused
  char* R                = (char*)alloc(4096ull*3072*4);
  unsigned short* qkv_out= (unsigned short*)R;
  unsigned short* attn_o = (unsigned short*)R;                       // 8.39 MB (after qkv dead)
  float* x1              = (float*)(R + (size_t)B_*T_*D_*2);         // 16.78 MB
  unsigned short* qb     = (unsigned short*)alloc(32ull*2048*64*2);
  unsigned short* kb     = (unsigned short*)alloc(32ull*2048*64*2);
  unsigned short* vt     = (unsigned short*)alloc(32ull*64*2048*2);
  unsigned short* mlp    = (unsigned short*)alloc(4096ull*4096*2);
  (void)ws_size; (void)in_sizes; (void)n_in; (void)out_size;

  k_conv_all<<<16384, 256, 0, stream>>>(qkv_w, proj_w, fc1_w, fc2_w, w_qkv, w_proj, w_fc1, w_fc2);

  k_ada<<<dim3(SIX_D/256, B_), 256, 0, stream>>>(cond, ada_w, ada_b, ada);
  k_norm_mod<<<B_*T_, 256, 0, stream>>>(x, norm1w, ada, 0, D_, h1);
  k_gemm_bt<EPI_BF16><<<dim3(3072/128, 4096/128), 256, 0, stream>>>(
      h1, w_qkv, B_*T_, 3*D_, D_, qkv_out, nullptr, nullptr, 0, nullptr);
  k_qkv_post<<<B_*T_*NH_, 64, 0, stream>>>(qkv_out, q_nw, k_nw, wptr, qb, kb);
  k_vtrans<<<dim3(T_/64, 32), 256, 0, stream>>>(qkv_out, vt);
  k_attn<<<512, 256, 0, stream>>>(qb, kb, vt, attn_o);
  k_gemm_bt64<EPI_RESID><<<dim3(1024/128, 4096/64), 256, 0, stream>>>(
      attn_o, w_proj, B_*T_, D_, D_, x1, x, ada, 2*D_, proj_b);
  k_norm_mod<<<B_*T_, 256, 0, stream>>>(x1, norm2w, ada, 3*D_, 4*D_, h1);
  k_gemm_fc1<<<dim3(HID_/64, 4096/128), 256, 0, stream>>>(h1, w_fc1, fc1_b, mlp);
  k_gemm_bt64<EPI_RESID><<<dim3(1024/128, 4096/64), 256, 0, stream>>>(
      mlp, w_fc2, B_*T_, D_, HID_, out, x1, ada, 5*D_, fc2_b);
}

// Round 6
// 608.749 us; speedup vs baseline: 1.0241x; 1.0241x over previous
//
#include <hip/hip_runtime.h>
#include <hip/hip_bf16.h>

#define B_   2
#define T_   2048
#define D_   1024
#define NH_  16
#define HD_  64
#define HID_ 4096
#define CD_  1024
#define SIX_D (6*D_)

typedef __bf16 bf16x8 __attribute__((ext_vector_type(8)));
typedef float  f32x4  __attribute__((ext_vector_type(4)));

__device__ __forceinline__ unsigned short f2bf(float f){
  union { float f; unsigned u; } v; v.f = f;
  unsigned r = v.u + 0x7FFFu + ((v.u >> 16) & 1u);
  return (unsigned short)(r >> 16);
}
__device__ __forceinline__ float bf2f(unsigned short u){
  union { unsigned x; float f; } v; v.x = ((unsigned)u) << 16; return v.f;
}

__device__ __forceinline__ void gl_lds16(const void* g, void* l){
  __builtin_amdgcn_global_load_lds(
      (__attribute__((address_space(1))) void*)const_cast<void*>(g),
      (__attribute__((address_space(3))) void*)l, 16, 0, 0);
}

// ---------------- all weights fp32 -> bf16, single launch ----------------
__global__ void k_conv_all(const float* __restrict__ s0, const float* __restrict__ s1,
                           const float* __restrict__ s2, const float* __restrict__ s3,
                           unsigned short* __restrict__ d0, unsigned short* __restrict__ d1,
                           unsigned short* __restrict__ d2, unsigned short* __restrict__ d3){
  int bid = blockIdx.x;
  const float* s; unsigned short* d; int base;
  if (bid < 3072)      { s = s0; d = d0; base = bid; }
  else if (bid < 4096) { s = s1; d = d1; base = bid - 3072; }
  else if (bid < 12288){ s = s2; d = d2; base = bid - 4096; }
  else                 { s = s3; d = d3; base = bid - 12288; }
  int i = base*256 + threadIdx.x;
  float4 v = reinterpret_cast<const float4*>(s)[i];
  ushort4 o;
  o.x = f2bf(v.x); o.y = f2bf(v.y); o.z = f2bf(v.z); o.w = f2bf(v.w);
  reinterpret_cast<ushort4*>(d)[i] = o;
}

// ---------------- ada = silu(cond) @ ada_w.T + ada_b ----------------
__global__ void k_ada(const float* __restrict__ cond, const float* __restrict__ ada_w,
                      const float* __restrict__ ada_b, float* __restrict__ ada){
  __shared__ float sc[CD_];
  int b = blockIdx.y;
  int tid = threadIdx.x;
  for (int i = tid; i < CD_; i += 256){
    float c = cond[b*CD_ + i];
    sc[i] = c / (1.f + __expf(-c));
  }
  __syncthreads();
  int col = blockIdx.x*256 + tid;
  const float* wr = ada_w + (size_t)col*CD_;
  float acc = 0.f;
  #pragma unroll 4
  for (int k = 0; k < CD_; k++) acc += sc[k]*wr[k];
  ada[b*SIX_D + col] = acc + ada_b[col];
}

// ---------------- rmsnorm + modulate -> bf16 ----------------
__global__ void k_norm_mod(const float* __restrict__ x, const float* __restrict__ w,
                           const float* __restrict__ ada, int sh_off, int sc_off,
                           unsigned short* __restrict__ out){
  int row = blockIdx.x;           // b*T + t
  int b = row >> 11;              // / T_
  int tid = threadIdx.x;
  float4 xv = reinterpret_cast<const float4*>(x + (size_t)row*D_)[tid];
  float ss = xv.x*xv.x + xv.y*xv.y + xv.z*xv.z + xv.w*xv.w;
  #pragma unroll
  for (int m = 32; m > 0; m >>= 1) ss += __shfl_xor(ss, m, 64);
  __shared__ float red[4];
  int wave = tid >> 6;
  if ((tid & 63) == 0) red[wave] = ss;
  __syncthreads();
  float tot = red[0]+red[1]+red[2]+red[3];
  float rn = rsqrtf(tot * (1.f/(float)D_) + 1e-6f);
  float4 wv  = reinterpret_cast<const float4*>(w)[tid];
  float4 scv = reinterpret_cast<const float4*>(ada + b*SIX_D + sc_off)[tid];
  float4 shv = reinterpret_cast<const float4*>(ada + b*SIX_D + sh_off)[tid];
  ushort4 o;
  o.x = f2bf(xv.x*rn*wv.x*(1.f+scv.x)+shv.x);
  o.y = f2bf(xv.y*rn*wv.y*(1.f+scv.y)+shv.y);
  o.z = f2bf(xv.z*rn*wv.z*(1.f+scv.z)+shv.z);
  o.w = f2bf(xv.w*rn*wv.w*(1.f+scv.w)+shv.w);
  reinterpret_cast<ushort4*>(out + (size_t)row*D_)[tid] = o;
}

// ---------------- 128x128 GEMM: C = A(MxK) * W(NxK)^T ----------------
enum { EPI_F32 = 0, EPI_RESID = 1, EPI_BF16 = 2 };

template<int EPI>
__launch_bounds__(256)
__global__ void k_gemm_bt(const unsigned short* __restrict__ A,
                          const unsigned short* __restrict__ W,
                          int M, int N, int K,
                          void* __restrict__ outp,
                          const float* __restrict__ resid,
                          const float* __restrict__ ada, int g_off,
                          const float* __restrict__ bias){
  __shared__ __align__(16) unsigned short As[128*32];
  __shared__ __align__(16) unsigned short Bs[128*32];
  const int tid = threadIdx.x;
  const int wave = tid >> 6, lane = tid & 63;
  const int wm = (wave >> 1)*64, wn = (wave & 1)*64;
  const int m0 = blockIdx.y*128, n0 = blockIdx.x*128;
  const int fr = lane & 15, fq = lane >> 4;
  f32x4 acc[4][4] = {};
  for (int k0 = 0; k0 < K; k0 += 32){
    __syncthreads();
    #pragma unroll
    for (int rr = 0; rr < 2; rr++){
      int idx = rr*256 + tid;
      int row = idx >> 2, c8 = (idx & 3)*8;
      gl_lds16(A + (size_t)(m0 + row)*K + k0 + c8, &As[(idx & ~63)*8]);
      gl_lds16(W + (size_t)(n0 + row)*K + k0 + c8, &Bs[(idx & ~63)*8]);
    }
    __syncthreads();
    bf16x8 af[4], bfr[4];
    #pragma unroll
    for (int i = 0; i < 4; i++){
      af[i]  = *(const bf16x8*)&As[(wm + i*16 + fr)*32 + fq*8];
      bfr[i] = *(const bf16x8*)&Bs[(wn + i*16 + fr)*32 + fq*8];
    }
    #pragma unroll
    for (int i = 0; i < 4; i++)
      #pragma unroll
      for (int j = 0; j < 4; j++)
        acc[i][j] = __builtin_amdgcn_mfma_f32_16x16x32_bf16(af[i], bfr[j], acc[i][j], 0,0,0);
  }
  #pragma unroll
  for (int i = 0; i < 4; i++){
    #pragma unroll
    for (int j = 0; j < 4; j++){
      int col = n0 + wn + j*16 + fr;
      #pragma unroll
      for (int r = 0; r < 4; r++){
        int row = m0 + wm + i*16 + fq*4 + r;
        float v = acc[i][j][r];
        if (EPI == EPI_F32){
          ((float*)outp)[(size_t)row*N + col] = v;
        } else if (EPI == EPI_BF16){
          ((unsigned short*)outp)[(size_t)row*N + col] = f2bf(v);
        } else {
          int b = row >> 11;
          float g = ada[b*SIX_D + g_off + col];
          ((float*)outp)[(size_t)row*N + col] = resid[(size_t)row*N + col] + g*(v + bias[col]);
        }
      }
    }
  }
}

// ---------------- 64x128 GEMM (for N=1024 shapes: proj, fc2) ----------------
template<int EPI>
__launch_bounds__(256)
__global__ void k_gemm_bt64(const unsigned short* __restrict__ A,
                            const unsigned short* __restrict__ W,
                            int M, int N, int K,
                            void* __restrict__ outp,
                            const float* __restrict__ resid,
                            const float* __restrict__ ada, int g_off,
                            const float* __restrict__ bias){
  __shared__ __align__(16) unsigned short As[64*32];
  __shared__ __align__(16) unsigned short Bs[128*32];
  const int tid = threadIdx.x;
  const int wave = tid >> 6, lane = tid & 63;
  const int wm = (wave >> 1)*32, wn = (wave & 1)*64;
  const int m0 = blockIdx.y*64, n0 = blockIdx.x*128;
  const int fr = lane & 15, fq = lane >> 4;
  f32x4 acc[2][4] = {};
  for (int k0 = 0; k0 < K; k0 += 32){
    __syncthreads();
    {
      int row = tid >> 2, c8 = (tid & 3)*8;
      gl_lds16(A + (size_t)(m0 + row)*K + k0 + c8, &As[(tid & ~63)*8]);
    }
    #pragma unroll
    for (int rr = 0; rr < 2; rr++){
      int idx = rr*256 + tid;
      int row = idx >> 2, c8 = (idx & 3)*8;
      gl_lds16(W + (size_t)(n0 + row)*K + k0 + c8, &Bs[(idx & ~63)*8]);
    }
    __syncthreads();
    bf16x8 af[2], bfr[4];
    #pragma unroll
    for (int i = 0; i < 2; i++)
      af[i]  = *(const bf16x8*)&As[(wm + i*16 + fr)*32 + fq*8];
    #pragma unroll
    for (int j = 0; j < 4; j++)
      bfr[j] = *(const bf16x8*)&Bs[(wn + j*16 + fr)*32 + fq*8];
    #pragma unroll
    for (int i = 0; i < 2; i++)
      #pragma unroll
      for (int j = 0; j < 4; j++)
        acc[i][j] = __builtin_amdgcn_mfma_f32_16x16x32_bf16(af[i], bfr[j], acc[i][j], 0,0,0);
  }
  #pragma unroll
  for (int i = 0; i < 2; i++){
    #pragma unroll
    for (int j = 0; j < 4; j++){
      int col = n0 + wn + j*16 + fr;
      #pragma unroll
      for (int r = 0; r < 4; r++){
        int row = m0 + wm + i*16 + fq*4 + r;
        float v = acc[i][j][r];
        if (EPI == EPI_F32){
          ((float*)outp)[(size_t)row*N + col] = v;
        } else if (EPI == EPI_BF16){
          ((unsigned short*)outp)[(size_t)row*N + col] = f2bf(v);
        } else {
          int b = row >> 11;
          float g = ada[b*SIX_D + g_off + col];
          ((float*)outp)[(size_t)row*N + col] = resid[(size_t)row*N + col] + g*(v + bias[col]);
        }
      }
    }
  }
}

// ---------------- fc1 dual 128x(64+64) with fused SwiGLU -> bf16 ----------------
__launch_bounds__(256)
__global__ void k_gemm_fc1(const unsigned short* __restrict__ A,
                           const unsigned short* __restrict__ W,   // (2*HID, D) bf16
                           const float* __restrict__ bias,          // (2*HID)
                           unsigned short* __restrict__ out){       // (B*T, HID) bf16
  __shared__ __align__(16) unsigned short As[128*32];
  __shared__ __align__(16) unsigned short Bv[64*32];
  __shared__ __align__(16) unsigned short Bg[64*32];
  const int K = D_;
  const int tid = threadIdx.x;
  const int wave = tid >> 6, lane = tid & 63;
  const int wm = (wave >> 1)*64, wn = (wave & 1)*32;
  const int m0 = blockIdx.y*128, n0 = blockIdx.x*64;
  const int fr = lane & 15, fq = lane >> 4;
  f32x4 accv[4][2] = {}, accg[4][2] = {};
  for (int k0 = 0; k0 < K; k0 += 32){
    __syncthreads();
    #pragma unroll
    for (int rr = 0; rr < 2; rr++){
      int idx = rr*256 + tid;
      int row = idx >> 2, c8 = (idx & 3)*8;
      gl_lds16(A + (size_t)(m0 + row)*K + k0 + c8, &As[(idx & ~63)*8]);
    }
    {
      int row = tid >> 2, c8 = (tid & 3)*8;
      gl_lds16(W + (size_t)(n0 + row)*K + k0 + c8,        &Bv[(tid & ~63)*8]);
      gl_lds16(W + (size_t)(HID_ + n0 + row)*K + k0 + c8, &Bg[(tid & ~63)*8]);
    }
    __syncthreads();
    bf16x8 af[4], bv[2], bg[2];
    #pragma unroll
    for (int i = 0; i < 4; i++)
      af[i] = *(const bf16x8*)&As[(wm + i*16 + fr)*32 + fq*8];
    #pragma unroll
    for (int j = 0; j < 2; j++){
      bv[j] = *(const bf16x8*)&Bv[(wn + j*16 + fr)*32 + fq*8];
      bg[j] = *(const bf16x8*)&Bg[(wn + j*16 + fr)*32 + fq*8];
    }
    #pragma unroll
    for (int i = 0; i < 4; i++)
      #pragma unroll
      for (int j = 0; j < 2; j++){
        accv[i][j] = __builtin_amdgcn_mfma_f32_16x16x32_bf16(af[i], bv[j], accv[i][j], 0,0,0);
        accg[i][j] = __builtin_amdgcn_mfma_f32_16x16x32_bf16(af[i], bg[j], accg[i][j], 0,0,0);
      }
  }
  #pragma unroll
  for (int i = 0; i < 4; i++){
    #pragma unroll
    for (int j = 0; j < 2; j++){
      int col = n0 + wn + j*16 + fr;
      #pragma unroll
      for (int r = 0; r < 4; r++){
        int row = m0 + wm + i*16 + fq*4 + r;
        float vv = accv[i][j][r] + bias[col];
        float gg = accg[i][j][r] + bias[HID_ + col];
        float h = vv * (gg / (1.f + __expf(-gg)));
        out[(size_t)row*HID_ + col] = f2bf(h);
      }
    }
  }
}

// ---------------- qkv(bf16) -> q,k with per-head rmsnorm + rope -> bf16 (B,NH,T,HD) ----------------
__global__ void k_qkv_post(const unsigned short* __restrict__ qkv,
                           const float* __restrict__ qw, const float* __restrict__ kw,
                           const int* __restrict__ wptr,
                           unsigned short* __restrict__ q, unsigned short* __restrict__ k){
  int idx = blockIdx.x;           // (b*T + t)*NH + h
  int h = idx & (NH_-1);
  int t = (idx >> 4) & (T_-1);
  int b = idx >> 15;
  int d = threadIdx.x;            // 0..63
  const unsigned short* base = qkv + (size_t)(b*T_ + t)*3072;
  float qv = bf2f(base[h*64 + d]);
  float kv = bf2f(base[1024 + h*64 + d]);
  float sq = qv*qv, sk = kv*kv;
  #pragma unroll
  for (int m = 32; m > 0; m >>= 1){ sq += __shfl_xor(sq, m, 64); sk += __shfl_xor(sk, m, 64); }
  qv *= rsqrtf(sq*(1.f/64.f) + 1e-6f) * qw[d];
  kv *= rsqrtf(sk*(1.f/64.f) + 1e-6f) * kw[d];
  int width = wptr[0];
  int yy = t / width, xx = t - yy*width;
  int coord = (d < 32) ? yy : xx;
  int fi = (d & 31) >> 1;
  float ifreq = __expf(-(float)fi * (9.210340371976184f/16.f));  // 10000^(-fi/16)
  float ang = (float)coord * ifreq;
  float cs = cosf(ang), sn = sinf(ang);
  float pq = __shfl_xor(qv, 1, 64);
  float pk = __shfl_xor(kv, 1, 64);
  float rq = (d & 1) ? pq : -pq;
  float rk = (d & 1) ? pk : -pk;
  qv = qv*cs + rq*sn;
  kv = kv*cs + rk*sn;
  size_t o = ((size_t)(b*NH_ + h)*T_ + t)*64 + d;
  q[o] = f2bf(qv); k[o] = f2bf(kv);
}

// ---------------- V transpose: qkv bf16 (b,t, 2048 + h*64+d) -> vt bf16 (b,h,d,t) ----------------
__global__ void k_vtrans(const unsigned short* __restrict__ qkv, unsigned short* __restrict__ vt){
  __shared__ __align__(16) unsigned short TT[64*64];  // [d][t], groups swizzled
  int bh = blockIdx.y, t0 = blockIdx.x*64;
  int b = bh >> 4, h = bh & 15;
  int tid = threadIdx.x;
  #pragma unroll
  for (int it = 0; it < 2; it++){
    int i2 = it*256 + tid;
    int t = i2 >> 3, c8 = (i2 & 7)*8;
    union { uint4 v; unsigned short u[8]; } ld;
    ld.v = *(const uint4*)(qkv + (size_t)(b*T_ + t0 + t)*3072 + 2048 + h*64 + c8);
    #pragma unroll
    for (int e = 0; e < 8; e++){
      int c = c8 + e;
      int gp = (t >> 3) ^ ((c >> 2) & 7);
      TT[c*64 + gp*8 + (t & 7)] = ld.u[e];
    }
  }
  __syncthreads();
  #pragma unroll
  for (int it = 0; it < 2; it++){
    int i2 = it*256 + tid;
    int d = i2 >> 3, g = i2 & 7;
    int gp = g ^ ((d >> 2) & 7);
    *(uint4*)(vt + ((size_t)(bh*64 + d)*T_ + t0 + g*8)) = *(const uint4*)&TT[d*64 + gp*8];
  }
}

// ---------------- flash attention: 64-row Q tiles, dbuf K/V, 1 barrier/tile ----------------
__launch_bounds__(256, 4)
__global__ void k_attn(const unsigned short* __restrict__ q,
                       const unsigned short* __restrict__ k,
                       const unsigned short* __restrict__ vt,
                       unsigned short* __restrict__ out){     // (B,T,D) bf16
  __shared__ __align__(16) unsigned short Kb[2][64*64];
  __shared__ __align__(16) unsigned short Vb[2][64*64];
  __shared__ __align__(16) unsigned short Ps[4][16*64];
  const int tid = threadIdx.x;
  const int wave = tid >> 6, lane = tid & 63;
  const int fr = lane & 15, fq = lane >> 4;
  // XCD-locality: bh in low 5 bits -> all 32 q-tiles of one head share id%8
  const int id = blockIdx.x;
  const int bh = id & 31, q0 = (id >> 5)*64;
  const unsigned short* kb = k  + (size_t)bh*T_*HD_;
  const unsigned short* vb = vt + (size_t)bh*HD_*T_;
  bf16x8 aq[2];
  {
    const unsigned short* qb = q + (size_t)bh*T_*HD_;
    #pragma unroll
    for (int kk = 0; kk < 2; kk++)
      aq[kk] = *(const bf16x8*)(qb + (size_t)(q0 + wave*16 + fr)*HD_ + kk*32 + fq*8);
  }
  f32x4 o[4] = {};
  float lsum[4] = {};
  uint4 rk[2], rv[2];
  // preload tile 0 into regs, stage to buf0
  #pragma unroll
  for (int it = 0; it < 2; it++){
    int i2 = it*256 + tid;
    int row = i2 >> 3, g = i2 & 7;
    rk[it] = ((const uint4*)kb)[row*8 + g];
    rv[it] = ((const uint4*)vb)[row*256 + g];
  }
  #pragma unroll
  for (int it = 0; it < 2; it++){
    int i2 = it*256 + tid;
    int row = i2 >> 3, g = i2 & 7, gp = g ^ (row & 7);
    ((uint4*)Kb[0])[row*8 + gp] = rk[it];
    ((uint4*)Vb[0])[row*8 + gp] = rv[it];
  }
  __syncthreads();
  for (int kt = 0; kt < T_; kt += 64){
    const int cur = (kt >> 6) & 1, nxt = cur ^ 1;
    const bool more = (kt + 64) < T_;
    if (more){
      #pragma unroll
      for (int it = 0; it < 2; it++){
        int i2 = it*256 + tid;
        int row = i2 >> 3, g = i2 & 7;
        rk[it] = ((const uint4*)kb)[(kt + 64 + row)*8 + g];
        rv[it] = ((const uint4*)vb)[row*256 + ((kt + 64) >> 3) + g];
      }
    }
    // S = Q K^T
    f32x4 s[4] = {};
    #pragma unroll
    for (int kk = 0; kk < 2; kk++){
      bf16x8 bk[4];
      #pragma unroll
      for (int j = 0; j < 4; j++)
        bk[j] = *(const bf16x8*)&Kb[cur][(j*16 + fr)*64 + ((kk*4 + fq) ^ (fr & 7))*8];
      #pragma unroll
      for (int j = 0; j < 4; j++)
        s[j] = __builtin_amdgcn_mfma_f32_16x16x32_bf16(aq[kk], bk[j], s[j], 0,0,0);
    }
    // fixed-shift softmax
    unsigned short* Pw = Ps[wave];
    #pragma unroll
    for (int j = 0; j < 4; j++)
      #pragma unroll
      for (int r = 0; r < 4; r++){
        float sv = s[j][r]*0.125f;
        sv = fminf(fmaxf(sv, -30.f), 30.f);
        float p = __expf(sv);
        lsum[r] += p;
        int row = fq*4 + r;
        int gp = (j*2 + (fr >> 3)) ^ (row & 7);
        Pw[row*64 + gp*8 + (fr & 7)] = f2bf(p);
      }
    // O += P V
    #pragma unroll
    for (int kk = 0; kk < 2; kk++){
      bf16x8 ap = *(const bf16x8*)&Pw[fr*64 + ((kk*4 + fq) ^ (fr & 7))*8];
      bf16x8 bv[4];
      #pragma unroll
      for (int dn = 0; dn < 4; dn++)
        bv[dn] = *(const bf16x8*)&Vb[cur][(dn*16 + fr)*64 + ((kk*4 + fq) ^ (fr & 7))*8];
      #pragma unroll
      for (int dn = 0; dn < 4; dn++)
        o[dn] = __builtin_amdgcn_mfma_f32_16x16x32_bf16(ap, bv[dn], o[dn], 0,0,0);
    }
    if (more){
      #pragma unroll
      for (int it = 0; it < 2; it++){
        int i2 = it*256 + tid;
        int row = i2 >> 3, g = i2 & 7, gp = g ^ (row & 7);
        ((uint4*)Kb[nxt])[row*8 + gp] = rk[it];
        ((uint4*)Vb[nxt])[row*8 + gp] = rv[it];
      }
      __syncthreads();
    }
  }
  // epilogue: row-sum reduce across fr lanes, normalize, repack via Ps, coalesced store
  #pragma unroll
  for (int r = 0; r < 4; r++){
    float l = lsum[r];
    #pragma unroll
    for (int m = 1; m < 16; m <<= 1) l += __shfl_xor(l, m, 64);
    lsum[r] = 1.f / l;
  }
  {
    unsigned short* Pw = Ps[wave];
    #pragma unroll
    for (int dn = 0; dn < 4; dn++)
      #pragma unroll
      for (int r = 0; r < 4; r++){
        int row = fq*4 + r;
        int gp = (dn*2 + (fr >> 3)) ^ (row & 7);
        Pw[row*64 + gp*8 + (fr & 7)] = f2bf(o[dn][r]*lsum[r]);
      }
  }
  __syncthreads();
  const int b = bh >> 4, h = bh & 15;
  const int rowg = tid >> 3, g = tid & 7;
  #pragma unroll
  for (int it = 0; it < 2; it++){
    int row = it*32 + rowg;
    int wsrc = row >> 4, r16 = row & 15;
    int gp = g ^ (r16 & 7);
    uint4 val = *(const uint4*)&Ps[wsrc][r16*64 + gp*8];
    *(uint4*)(out + (size_t)(b*T_ + q0 + row)*D_ + h*64 + g*8) = val;
  }
}

extern "C" void kernel_launch(void* const* d_in, const int* in_sizes, int n_in,
                              void* d_out, int out_size, void* d_ws, size_t ws_size,
                              hipStream_t stream){
  const float* x      = (const float*)d_in[0];
  const float* cond   = (const float*)d_in[1];
  const float* norm1w = (const float*)d_in[2];
  const float* qkv_w  = (const float*)d_in[3];
  const float* q_nw   = (const float*)d_in[4];
  const float* k_nw   = (const float*)d_in[5];
  const float* proj_w = (const float*)d_in[6];
  const float* proj_b = (const float*)d_in[7];
  const float* norm2w = (const float*)d_in[8];
  const float* fc1_w  = (const float*)d_in[9];
  const float* fc1_b  = (const float*)d_in[10];
  const float* fc2_w  = (const float*)d_in[11];
  const float* fc2_b  = (const float*)d_in[12];
  const float* ada_w  = (const float*)d_in[13];
  const float* ada_b  = (const float*)d_in[14];
  const int*   wptr   = (const int*)d_in[16];
  float* out = (float*)d_out;

  char* ws = (char*)d_ws;
  size_t off = 0;
  auto alloc = [&](size_t bytes)->void*{
    void* p = ws + off; off += (bytes + 255) & ~(size_t)255; return p;
  };
  unsigned short* w_qkv  = (unsigned short*)alloc(3072ull*1024*2);
  unsigned short* w_proj = (unsigned short*)alloc(1024ull*1024*2);
  unsigned short* w_fc1  = (unsigned short*)alloc(8192ull*1024*2);
  unsigned short* w_fc2  = (unsigned short*)alloc(1024ull*4096*2);
  float* ada             = (float*)alloc((size_t)B_*SIX_D*4);
  unsigned short* h1     = (unsigned short*)alloc(4096ull*1024*2);
  // region R: qkv_out bf16 (25 MB) lives until k_vtrans; afterwards reused
  char* R                = (char*)alloc(4096ull*3072*4);
  unsigned short* qkv_out= (unsigned short*)R;
  unsigned short* attn_o = (unsigned short*)R;                       // 8.39 MB (after qkv dead)
  float* x1              = (float*)(R + (size_t)B_*T_*D_*2);         // 16.78 MB
  unsigned short* qb     = (unsigned short*)alloc(32ull*2048*64*2);
  unsigned short* kb     = (unsigned short*)alloc(32ull*2048*64*2);
  unsigned short* vt     = (unsigned short*)alloc(32ull*64*2048*2);
  unsigned short* mlp    = (unsigned short*)alloc(4096ull*4096*2);
  (void)ws_size; (void)in_sizes; (void)n_in; (void)out_size;

  k_conv_all<<<16384, 256, 0, stream>>>(qkv_w, proj_w, fc1_w, fc2_w, w_qkv, w_proj, w_fc1, w_fc2);

  k_ada<<<dim3(SIX_D/256, B_), 256, 0, stream>>>(cond, ada_w, ada_b, ada);
  k_norm_mod<<<B_*T_, 256, 0, stream>>>(x, norm1w, ada, 0, D_, h1);
  k_gemm_bt<EPI_BF16><<<dim3(3072/128, 4096/128), 256, 0, stream>>>(
      h1, w_qkv, B_*T_, 3*D_, D_, qkv_out, nullptr, nullptr, 0, nullptr);
  k_qkv_post<<<B_*T_*NH_, 64, 0, stream>>>(qkv_out, q_nw, k_nw, wptr, qb, kb);
  k_vtrans<<<dim3(T_/64, 32), 256, 0, stream>>>(qkv_out, vt);
  k_attn<<<1024, 256, 0, stream>>>(qb, kb, vt, attn_o);
  k_gemm_bt64<EPI_RESID><<<dim3(1024/128, 4096/64), 256, 0, stream>>>(
      attn_o, w_proj, B_*T_, D_, D_, x1, x, ada, 2*D_, proj_b);
  k_norm_mod<<<B_*T_, 256, 0, stream>>>(x1, norm2w, ada, 3*D_, 4*D_, h1);
  k_gemm_fc1<<<dim3(HID_/64, 4096/128), 256, 0, stream>>>(h1, w_fc1, fc1_b, mlp);
  k_gemm_bt64<EPI_RESID><<<dim3(1024/128, 4096/64), 256, 0, stream>>>(
      mlp, w_fc2, B_*T_, D_, HID_, out, x1, ada, 5*D_, fc2_b);
}